// Round 2
// baseline (586.378 us; speedup 1.0000x reference)
//
#include <hip/hip_runtime.h>
#include <hip/hip_bf16.h>

typedef __attribute__((ext_vector_type(8))) short bf16x8;   // 8 bf16 in 4 VGPRs
typedef __attribute__((ext_vector_type(4))) float f32x4;    // MFMA accumulator

#define S77 77
#define NQ  80
#define CH  128
#define CIN 256

__device__ __forceinline__ float bf2f(unsigned short b) {
    union { unsigned int u; float f; } v; v.u = ((unsigned int)b) << 16; return v.f;
}
__device__ __forceinline__ unsigned short f2bf(float f) {
    union { float f; unsigned int u; } v; v.f = f;
    unsigned int u = v.u;
    return (unsigned short)((u + 0x7FFFu + ((u >> 16) & 1u)) >> 16);
}
__device__ __forceinline__ bf16x8 load_cvt8(const float* __restrict__ p) {
    const float4 f0 = *(const float4*)p;
    const float4 f1 = *(const float4*)(p + 4);
    bf16x8 r;
    r[0] = (short)f2bf(f0.x); r[1] = (short)f2bf(f0.y);
    r[2] = (short)f2bf(f0.z); r[3] = (short)f2bf(f0.w);
    r[4] = (short)f2bf(f1.x); r[5] = (short)f2bf(f1.y);
    r[6] = (short)f2bf(f1.z); r[7] = (short)f2bf(f1.w);
    return r;
}

// ws layout (bf16 elems): WqT [128][256] @0, WkT [128][256] @32768, WvT [128][128] @65536
__global__ void transpose_weights(const float* __restrict__ Wq,
                                  const float* __restrict__ Wk,
                                  const float* __restrict__ Wv,
                                  unsigned short* __restrict__ ws) {
    int t = blockIdx.x * 256 + threadIdx.x;
    if (t < 32768) {                // Wq (256x128) -> WqT
        int k = t >> 7, c = t & 127;
        ws[c * 256 + k] = f2bf(Wq[t]);
    } else if (t < 65536) {         // Wk
        int u = t - 32768; int k = u >> 7, c = u & 127;
        ws[32768 + c * 256 + k] = f2bf(Wk[u]);
    } else if (t < 81920) {         // Wv (128x128) -> WvT
        int u = t - 65536; int k = u >> 7, c = u & 127;
        ws[65536 + c * 128 + k] = f2bf(Wv[u]);
    }
}

__global__ __launch_bounds__(256, 1)
void attn_kernel(const float* __restrict__ query,   // (4,80,24,24,256) f32
                 const float* __restrict__ x,       // (2304,77,128) f32
                 const float* __restrict__ guid,    // (2304,77,128) f32
                 const unsigned short* __restrict__ wT,  // transposed bf16 weights in ws
                 const float* __restrict__ bq,
                 const float* __restrict__ bk,
                 const float* __restrict__ bv,
                 float* __restrict__ out)            // (2304,128) f32
{
    const int n    = blockIdx.x;
    const int tid  = threadIdx.x;
    const int w    = tid >> 6;      // wave 0..3
    const int lane = tid & 63;
    const int quad = lane >> 4;     // 0..3
    const int mr   = lane & 15;

    const int b  = n / 576;         // batch
    const int hw = n % 576;         // hh*24+ww

    __shared__ union {
        struct { unsigned short KfT[128 * 96]; unsigned short VsT[128 * 96]; } p; // 49152 B
        float Qf[NQ * CH];                                                        // 40960 B
    } sm;
    __shared__ float KV[8][16][16];
    __shared__ float Ksum[128];
    __shared__ float Zl[NQ * 8];
    __shared__ float Qb[128];

    const unsigned short* WqT = wT;
    const unsigned short* WkT = wT + 32768;
    const unsigned short* WvT = wT + 65536;

    const int n0 = 2 * w, n1 = 2 * w + 1;   // this wave's two 16-col output tiles
    const bf16x8 aZ = {0, 0, 0, 0, 0, 0, 0, 0};
    const f32x4  cZ = {0.f, 0.f, 0.f, 0.f};

    const float* xg = x    + (size_t)n * S77 * CH;
    const float* gg = guid + (size_t)n * S77 * CH;

    // ---------------- Phase A1: Kf = elu([x|g]@Wk + bk)+1  -> KfT (transposed, bf16)
    {
        f32x4 acc[5][2];
        for (int m = 0; m < 5; ++m) { acc[m][0] = cZ; acc[m][1] = cZ; }
        for (int kk = 0; kk < 8; ++kk) {
            const int kc = kk * 32 + quad * 8;                 // global k of this lane's 8 elems
            bf16x8 b0 = *(const bf16x8*)(WkT + (n0 * 16 + mr) * 256 + kc);
            bf16x8 b1 = *(const bf16x8*)(WkT + (n1 * 16 + mr) * 256 + kc);
            const float* src = (kk < 4) ? (xg + kc) : (gg + (kc - 128));
            for (int m = 0; m < 5; ++m) {
                const int s = m * 16 + mr;
                bf16x8 a = (s < S77) ? load_cvt8(src + s * CH) : aZ;
                acc[m][0] = __builtin_amdgcn_mfma_f32_16x16x32_bf16(a, b0, acc[m][0], 0, 0, 0);
                acc[m][1] = __builtin_amdgcn_mfma_f32_16x16x32_bf16(a, b1, acc[m][1], 0, 0, 0);
            }
        }
        for (int m = 0; m < 5; ++m)
            for (int t2 = 0; t2 < 2; ++t2) {
                const int colc = (2 * w + t2) * 16 + mr;
                const float bias = bk[colc];
                for (int r = 0; r < 4; ++r) {
                    const int srow = m * 16 + quad * 4 + r;    // C-layout: row=quad*4+r, col=lane&15
                    float v = acc[m][t2][r] + bias;
                    v = (v > 0.f) ? (v + 1.f) : __expf(v);     // elu(v)+1
                    sm.p.KfT[colc * 96 + srow] = f2bf(v);
                }
            }
    }

    // ---------------- Phase A2: V = x@Wv + bv -> VsT (transposed, bf16)
    {
        f32x4 acc[5][2];
        for (int m = 0; m < 5; ++m) { acc[m][0] = cZ; acc[m][1] = cZ; }
        for (int kk = 0; kk < 4; ++kk) {
            const int kc = kk * 32 + quad * 8;
            bf16x8 b0 = *(const bf16x8*)(WvT + (n0 * 16 + mr) * 128 + kc);
            bf16x8 b1 = *(const bf16x8*)(WvT + (n1 * 16 + mr) * 128 + kc);
            for (int m = 0; m < 5; ++m) {
                const int s = m * 16 + mr;
                bf16x8 a = (s < S77) ? load_cvt8(xg + s * CH + kc) : aZ;
                acc[m][0] = __builtin_amdgcn_mfma_f32_16x16x32_bf16(a, b0, acc[m][0], 0, 0, 0);
                acc[m][1] = __builtin_amdgcn_mfma_f32_16x16x32_bf16(a, b1, acc[m][1], 0, 0, 0);
            }
        }
        for (int m = 0; m < 5; ++m)
            for (int t2 = 0; t2 < 2; ++t2) {
                const int colc = (2 * w + t2) * 16 + mr;
                const float bias = bv[colc];
                for (int r = 0; r < 4; ++r) {
                    const int srow = m * 16 + quad * 4 + r;
                    sm.p.VsT[colc * 96 + srow] = f2bf(acc[m][t2][r] + bias);
                }
            }
    }
    __syncthreads();

    // ---------------- Phase B: zero pad rows s=77..95 (feature map of pad rows is NOT zero)
    for (int i = tid; i < 128 * 19; i += 256) {
        const int c = i / 19, s = 77 + (i % 19);
        sm.p.KfT[c * 96 + s] = 0;
        sm.p.VsT[c * 96 + s] = 0;
    }
    __syncthreads();

    // ---------------- Phase C: KV_h = Kf_h^T @ V_h (K=96, zero-padded) ; Ksum
    for (int i = 0; i < 2; ++i) {
        const int h = 2 * w + i;
        f32x4 acc = cZ;
        for (int ks = 0; ks < 3; ++ks) {
            const int sc = ks * 32 + quad * 8;
            bf16x8 a  = *(const bf16x8*)(sm.p.KfT + (h * 16 + mr) * 96 + sc); // A[d][s]=Kf[s][h16+d]
            bf16x8 bb = *(const bf16x8*)(sm.p.VsT + (h * 16 + mr) * 96 + sc); // B[s][e]=V[s][h16+e]
            acc = __builtin_amdgcn_mfma_f32_16x16x32_bf16(a, bb, acc, 0, 0, 0);
        }
        for (int r = 0; r < 4; ++r) KV[h][quad * 4 + r][mr] = acc[r];
    }
    if (tid < 128) {
        float s = 0.f;
        int sidx = tid % 77;                    // rotate start to avoid 32-way bank conflicts
        for (int i = 0; i < S77; ++i) {
            s += bf2f(sm.p.KfT[tid * 96 + sidx]);
            if (++sidx == 77) sidx = 0;
        }
        Ksum[tid] = s;
    }
    __syncthreads();

    // ---------------- Phase D: Qf = elu(qin@Wq + bq)+1 -> sm.Qf (f32, unions over KfT/VsT)
    {
        f32x4 acc[5][2];
        for (int m = 0; m < 5; ++m) { acc[m][0] = cZ; acc[m][1] = cZ; }
        for (int kk = 0; kk < 8; ++kk) {
            const int kc = kk * 32 + quad * 8;
            bf16x8 b0 = *(const bf16x8*)(WqT + (n0 * 16 + mr) * 256 + kc);
            bf16x8 b1 = *(const bf16x8*)(WqT + (n1 * 16 + mr) * 256 + kc);
            for (int m = 0; m < 5; ++m) {
                const int l = m * 16 + mr;   // 0..79, always valid
                const float* src = query + ((size_t)(b * 80 + l) * 576 + hw) * 256 + kc;
                bf16x8 a = load_cvt8(src);
                acc[m][0] = __builtin_amdgcn_mfma_f32_16x16x32_bf16(a, b0, acc[m][0], 0, 0, 0);
                acc[m][1] = __builtin_amdgcn_mfma_f32_16x16x32_bf16(a, b1, acc[m][1], 0, 0, 0);
            }
        }
        __syncthreads();  // Ksum consumers of KfT (Phase C) are done; safe to overwrite union
        for (int m = 0; m < 5; ++m)
            for (int t2 = 0; t2 < 2; ++t2) {
                const int colc = (2 * w + t2) * 16 + mr;
                const float bias = bq[colc];
                for (int r = 0; r < 4; ++r) {
                    const int lrow = m * 16 + quad * 4 + r;
                    float v = acc[m][t2][r] + bias;
                    v = (v > 0.f) ? (v + 1.f) : __expf(v);
                    sm.Qf[lrow * 128 + colc] = v;
                }
            }
    }
    __syncthreads();

    // ---------------- Phase E: z_{l,h} = 1/(Qf_l,h . Ksum_h + eps)
    for (int idx = tid; idx < NQ * 8; idx += 256) {
        const int l = idx >> 3, h = idx & 7;
        float d = 0.f;
        for (int j = 0; j < 16; ++j) d += sm.Qf[l * 128 + h * 16 + j] * Ksum[h * 16 + j];
        Zl[idx] = 1.f / (d + 1e-6f);
    }
    __syncthreads();

    // ---------------- Phase F: Qbar_h,d = sum_l z_{l,h} Qf[l][h16+d];  out = (1/N) Qbar @ KV
    if (tid < 128) {
        const int h = tid >> 4;
        float s = 0.f;
        for (int l = 0; l < NQ; ++l) s += Zl[l * 8 + h] * sm.Qf[l * 128 + tid];
        Qb[tid] = s;
    }
    __syncthreads();
    if (tid < 128) {
        const int h = tid >> 4, e = tid & 15;
        float o = 0.f;
        for (int d2 = 0; d2 < 16; ++d2) o += Qb[h * 16 + d2] * KV[h][d2][e];
        out[(size_t)n * 128 + tid] = o * (1.f / 80.f);
    }
}

extern "C" void kernel_launch(void* const* d_in, const int* in_sizes, int n_in,
                              void* d_out, int out_size, void* d_ws, size_t ws_size,
                              hipStream_t stream) {
    const float* query = (const float*)d_in[0];
    const float* x     = (const float*)d_in[1];
    const float* g     = (const float*)d_in[2];
    const float* Wq    = (const float*)d_in[3];
    const float* bq    = (const float*)d_in[4];
    const float* Wk    = (const float*)d_in[5];
    const float* bk    = (const float*)d_in[6];
    const float* Wv    = (const float*)d_in[7];
    const float* bv    = (const float*)d_in[8];
    float* out = (float*)d_out;
    unsigned short* ws = (unsigned short*)d_ws;   // 163,840 B used

    hipLaunchKernelGGL(transpose_weights, dim3(320), dim3(256), 0, stream, Wq, Wk, Wv, ws);
    hipLaunchKernelGGL(attn_kernel, dim3(2304), dim3(256), 0, stream,
                       query, x, g, ws, bq, bk, bv, out);
}

// Round 3
// 561.477 us; speedup vs baseline: 1.0443x; 1.0443x over previous
//
#include <hip/hip_runtime.h>
#include <hip/hip_bf16.h>

typedef __attribute__((ext_vector_type(8))) short bf16x8;   // 8 bf16 in 4 VGPRs
typedef __attribute__((ext_vector_type(4))) float f32x4;    // MFMA accumulator

#define S77 77
#define NQ  80
#define CH  128
#define KSTR 104   // KfT/VsT row stride in shorts (208 B, 16B-aligned, bank-spread)
#define QSTR 132   // Qf row stride in floats (quad-pairs 16 banks apart -> 2-way free)

__device__ __forceinline__ unsigned short f2bf(float f) {
    union { float f; unsigned int u; } v; v.f = f;
    unsigned int u = v.u;
    return (unsigned short)((u + 0x7FFFu + ((u >> 16) & 1u)) >> 16);
}
__device__ __forceinline__ bf16x8 load_cvt8(const float* __restrict__ p) {
    const float4 f0 = *(const float4*)p;
    const float4 f1 = *(const float4*)(p + 4);
    bf16x8 r;
    r[0] = (short)f2bf(f0.x); r[1] = (short)f2bf(f0.y);
    r[2] = (short)f2bf(f0.z); r[3] = (short)f2bf(f0.w);
    r[4] = (short)f2bf(f1.x); r[5] = (short)f2bf(f1.y);
    r[6] = (short)f2bf(f1.z); r[7] = (short)f2bf(f1.w);
    return r;
}

// ws layout (bf16 elems): WqT [128][256] @0, WkT [128][256] @32768, WvT [128][128] @65536
__global__ void transpose_weights(const float* __restrict__ Wq,
                                  const float* __restrict__ Wk,
                                  const float* __restrict__ Wv,
                                  unsigned short* __restrict__ ws) {
    int t = blockIdx.x * 256 + threadIdx.x;
    if (t < 32768) {                // Wq (256x128) -> WqT
        int k = t >> 7, c = t & 127;
        ws[c * 256 + k] = f2bf(Wq[t]);
    } else if (t < 65536) {         // Wk
        int u = t - 32768; int k = u >> 7, c = u & 127;
        ws[32768 + c * 256 + k] = f2bf(Wk[u]);
    } else if (t < 81920) {         // Wv (128x128) -> WvT
        int u = t - 65536; int k = u >> 7, c = u & 127;
        ws[65536 + c * 128 + k] = f2bf(Wv[u]);
    }
}

__global__ __launch_bounds__(512, 4)
void attn_kernel(const float* __restrict__ query,   // (4,80,24,24,256) f32
                 const float* __restrict__ x,       // (2304,77,128) f32
                 const float* __restrict__ guid,    // (2304,77,128) f32
                 const unsigned short* __restrict__ wT,  // transposed bf16 weights
                 const float* __restrict__ bq,
                 const float* __restrict__ bk,
                 const float* __restrict__ bv,
                 float* __restrict__ out)            // (2304,128) f32
{
    const int n    = blockIdx.x;
    const int tid  = threadIdx.x;
    const int wid  = tid >> 6;      // wave 0..7
    const int lane = tid & 63;
    const int quad = lane >> 4;     // 0..3
    const int mr   = lane & 15;

    const int b  = n / 576;         // batch
    const int hw = n % 576;         // hh*24+ww

    __shared__ union {
        struct { unsigned short KfT[128 * KSTR]; unsigned short VsT[128 * KSTR]; } p; // 53248 B
        float Qf[NQ * QSTR];                                                          // 42240 B
    } sm;
    __shared__ float KV[8][16][16];   // 8192 B
    __shared__ float Ksum[128];
    __shared__ float Zl[NQ * 8];
    __shared__ float Qb[128];
    // total LDS = 65,024 B -> 2 blocks/CU, 16 waves/CU

    const unsigned short* WqT = wT;
    const unsigned short* WkT = wT + 32768;
    const unsigned short* WvT = wT + 65536;

    const bf16x8 aZ = {0, 0, 0, 0, 0, 0, 0, 0};
    const f32x4  cZ = {0.f, 0.f, 0.f, 0.f};

    const float* xg = x    + (size_t)n * S77 * CH;
    const float* gg = guid + (size_t)n * S77 * CH;

    f32x4 accD[5][2];   // consumer waves' Q-GEMM accumulators (live across phase C)

    if (wid < 4) {
        // ================= PRODUCER waves 0-3: K GEMM, V GEMM =================
        const int w  = wid;
        const int n0 = 2 * w, n1 = 2 * w + 1;

        // ---- A1: Kf = elu([x|g]@Wk + bk)+1 -> KfT (bf16, transposed); Ksum via shuffle
        {
            f32x4 acc[5][2];
            #pragma unroll
            for (int m = 0; m < 5; ++m) { acc[m][0] = cZ; acc[m][1] = cZ; }
            #pragma unroll
            for (int kk = 0; kk < 8; ++kk) {
                const int kc = kk * 32 + quad * 8;
                bf16x8 b0 = *(const bf16x8*)(WkT + (n0 * 16 + mr) * 256 + kc);
                bf16x8 b1 = *(const bf16x8*)(WkT + (n1 * 16 + mr) * 256 + kc);
                const float* src = (kk < 4) ? (xg + kc) : (gg + (kc - 128));
                #pragma unroll
                for (int m = 0; m < 5; ++m) {
                    const int s = m * 16 + mr;
                    bf16x8 a = (s < S77) ? load_cvt8(src + s * CH) : aZ;
                    acc[m][0] = __builtin_amdgcn_mfma_f32_16x16x32_bf16(a, b0, acc[m][0], 0, 0, 0);
                    acc[m][1] = __builtin_amdgcn_mfma_f32_16x16x32_bf16(a, b1, acc[m][1], 0, 0, 0);
                }
            }
            const float bias0 = bk[n0 * 16 + mr];
            const float bias1 = bk[n1 * 16 + mr];
            float ks0 = 0.f, ks1 = 0.f;
            #pragma unroll
            for (int m = 0; m < 5; ++m)
                #pragma unroll
                for (int t2 = 0; t2 < 2; ++t2) {
                    const int colc = (2 * w + t2) * 16 + mr;
                    const float bias = t2 ? bias1 : bias0;
                    #pragma unroll
                    for (int r = 0; r < 4; ++r) {
                        const int srow = m * 16 + quad * 4 + r;
                        float v = 0.f;
                        if (srow < S77) {
                            v = acc[m][t2][r] + bias;
                            v = (v > 0.f) ? (v + 1.f) : __expf(v);   // elu+1
                        }
                        sm.p.KfT[colc * KSTR + srow] = f2bf(v);
                        if (t2) ks1 += v; else ks0 += v;
                    }
                }
            // cross-quad reduce (lanes mr, mr+16, mr+32, mr+48)
            ks0 += __shfl_down(ks0, 32); ks0 += __shfl_down(ks0, 16);
            ks1 += __shfl_down(ks1, 32); ks1 += __shfl_down(ks1, 16);
            if (lane < 16) {
                Ksum[n0 * 16 + mr] = ks0;
                Ksum[n1 * 16 + mr] = ks1;
            }
        }

        // ---- A2: V = x@Wv + bv -> VsT (bf16, transposed)
        {
            f32x4 acc[5][2];
            #pragma unroll
            for (int m = 0; m < 5; ++m) { acc[m][0] = cZ; acc[m][1] = cZ; }
            #pragma unroll
            for (int kk = 0; kk < 4; ++kk) {
                const int kc = kk * 32 + quad * 8;
                bf16x8 b0 = *(const bf16x8*)(WvT + (n0 * 16 + mr) * 128 + kc);
                bf16x8 b1 = *(const bf16x8*)(WvT + (n1 * 16 + mr) * 128 + kc);
                #pragma unroll
                for (int m = 0; m < 5; ++m) {
                    const int s = m * 16 + mr;
                    bf16x8 a = (s < S77) ? load_cvt8(xg + s * CH + kc) : aZ;
                    acc[m][0] = __builtin_amdgcn_mfma_f32_16x16x32_bf16(a, b0, acc[m][0], 0, 0, 0);
                    acc[m][1] = __builtin_amdgcn_mfma_f32_16x16x32_bf16(a, b1, acc[m][1], 0, 0, 0);
                }
            }
            const float bias0 = bv[n0 * 16 + mr];
            const float bias1 = bv[n1 * 16 + mr];
            #pragma unroll
            for (int m = 0; m < 5; ++m)
                #pragma unroll
                for (int t2 = 0; t2 < 2; ++t2) {
                    const int colc = (2 * w + t2) * 16 + mr;
                    const float bias = t2 ? bias1 : bias0;
                    #pragma unroll
                    for (int r = 0; r < 4; ++r) {
                        const int srow = m * 16 + quad * 4 + r;
                        float v = (srow < S77) ? (acc[m][t2][r] + bias) : 0.f;
                        sm.p.VsT[colc * KSTR + srow] = f2bf(v);
                    }
                }
        }

        // ---- zero pad rows 80..95 (epilogues cover rows 0..79 only)
        for (int i = tid; i < 2048; i += 256) {
            const int c = i >> 4, s = 80 + (i & 15);
            sm.p.KfT[c * KSTR + s] = 0;
            sm.p.VsT[c * KSTR + s] = 0;
        }
    } else {
        // ================= CONSUMER waves 4-7: Q GEMM into registers =================
        const int w2 = wid - 4;
        const int n0 = 2 * w2, n1 = 2 * w2 + 1;
        #pragma unroll
        for (int m = 0; m < 5; ++m) { accD[m][0] = cZ; accD[m][1] = cZ; }
        #pragma unroll
        for (int kk = 0; kk < 8; ++kk) {
            const int kc = kk * 32 + quad * 8;
            bf16x8 b0 = *(const bf16x8*)(WqT + (n0 * 16 + mr) * 256 + kc);
            bf16x8 b1 = *(const bf16x8*)(WqT + (n1 * 16 + mr) * 256 + kc);
            #pragma unroll
            for (int m = 0; m < 5; ++m) {
                const int l = m * 16 + mr;   // 0..79
                const float* src = query + ((size_t)(b * 80 + l) * 576 + hw) * 256 + kc;
                bf16x8 a = load_cvt8(src);
                accD[m][0] = __builtin_amdgcn_mfma_f32_16x16x32_bf16(a, b0, accD[m][0], 0, 0, 0);
                accD[m][1] = __builtin_amdgcn_mfma_f32_16x16x32_bf16(a, b1, accD[m][1], 0, 0, 0);
            }
        }
    }
    __syncthreads();   // #1: KfT/VsT (incl. zero pad) ready

    // ---- Phase C: each wave computes one head's KV = Kf_h^T @ V_h (K=96, padded)
    {
        const int h = wid;
        f32x4 acc = cZ;
        #pragma unroll
        for (int ks = 0; ks < 3; ++ks) {
            const int sc = ks * 32 + quad * 8;
            bf16x8 a  = *(const bf16x8*)(sm.p.KfT + (h * 16 + mr) * KSTR + sc);
            bf16x8 bb = *(const bf16x8*)(sm.p.VsT + (h * 16 + mr) * KSTR + sc);
            acc = __builtin_amdgcn_mfma_f32_16x16x32_bf16(a, bb, acc, 0, 0, 0);
        }
        #pragma unroll
        for (int r = 0; r < 4; ++r) KV[h][quad * 4 + r][mr] = acc[r];
    }
    __syncthreads();   // #2: KV done; KfT/VsT dead -> Qf (union) may be written

    if (wid >= 4) {
        // ---- D epilogue: Qf = elu(qin@Wq + bq)+1 (f32, stride QSTR)
        const int w2 = wid - 4;
        const float bias0 = bq[(2 * w2) * 16 + mr];
        const float bias1 = bq[(2 * w2 + 1) * 16 + mr];
        #pragma unroll
        for (int m = 0; m < 5; ++m)
            #pragma unroll
            for (int t2 = 0; t2 < 2; ++t2) {
                const int colc = (2 * w2 + t2) * 16 + mr;
                const float bias = t2 ? bias1 : bias0;
                #pragma unroll
                for (int r = 0; r < 4; ++r) {
                    const int lrow = m * 16 + quad * 4 + r;
                    float v = accD[m][t2][r] + bias;
                    v = (v > 0.f) ? (v + 1.f) : __expf(v);
                    sm.Qf[lrow * QSTR + colc] = v;
                }
            }
    }
    __syncthreads();   // #3: Qf ready

    // ---- Phase E: z_{l,h} = 1/(Qf_l,h . Ksum_h + eps)
    for (int idx = tid; idx < NQ * 8; idx += 512) {
        const int l = idx >> 3, h = idx & 7;
        float d = 0.f;
        #pragma unroll
        for (int j = 0; j < 16; ++j) d += sm.Qf[l * QSTR + h * 16 + j] * Ksum[h * 16 + j];
        Zl[idx] = 1.f / (d + 1e-6f);
    }
    __syncthreads();   // #4: Zl ready

    // ---- Phase F: Qbar then out = (1/N) * Qbar @ KV
    if (tid < 128) {
        const int h = tid >> 4;
        float s = 0.f;
        for (int l = 0; l < NQ; ++l) s += Zl[l * 8 + h] * sm.Qf[l * QSTR + tid];
        Qb[tid] = s;
    }
    __syncthreads();   // #5: Qb ready
    if (tid < 128) {
        const int h = tid >> 4, e = tid & 15;
        float o = 0.f;
        #pragma unroll
        for (int d2 = 0; d2 < 16; ++d2) o += Qb[h * 16 + d2] * KV[h][d2][e];
        out[(size_t)n * 128 + tid] = o * (1.f / 80.f);
    }
}

extern "C" void kernel_launch(void* const* d_in, const int* in_sizes, int n_in,
                              void* d_out, int out_size, void* d_ws, size_t ws_size,
                              hipStream_t stream) {
    const float* query = (const float*)d_in[0];
    const float* x     = (const float*)d_in[1];
    const float* g     = (const float*)d_in[2];
    const float* Wq    = (const float*)d_in[3];
    const float* bq    = (const float*)d_in[4];
    const float* Wk    = (const float*)d_in[5];
    const float* bk    = (const float*)d_in[6];
    const float* Wv    = (const float*)d_in[7];
    const float* bv    = (const float*)d_in[8];
    float* out = (float*)d_out;
    unsigned short* ws = (unsigned short*)d_ws;   // 163,840 B used

    hipLaunchKernelGGL(transpose_weights, dim3(320), dim3(256), 0, stream, Wq, Wk, Wv, ws);
    hipLaunchKernelGGL(attn_kernel, dim3(2304), dim3(512), 0, stream,
                       query, x, g, ws, bq, bk, bv, out);
}

// Round 4
// 481.391 us; speedup vs baseline: 1.2181x; 1.1664x over previous
//
#include <hip/hip_runtime.h>
#include <hip/hip_bf16.h>

typedef __attribute__((ext_vector_type(8))) short bf16x8;   // 8 bf16 in 4 VGPRs
typedef __attribute__((ext_vector_type(4))) float f32x4;    // MFMA accumulator

#define S77  77
#define NQ   80
#define KSTR 104   // KfT/VsT row stride (shorts); mult of 8 -> b128-aligned, bank-spread
#define XSTR 264   // XGb/Qb16 row stride (shorts); mult of 8, +8 pad breaks pow2 conflicts
#define QSTR 132   // Qf row stride (floats)

__device__ __forceinline__ unsigned int cvt_pk(float a, float b) {
    union { __hip_bfloat162 h; unsigned int u; } c;
    c.h = __float22bfloat162_rn(make_float2(a, b));   // v_cvt_pk_bf16_f32
    return c.u;
}
__device__ __forceinline__ unsigned short f2bf(float f) {
    union { __hip_bfloat16 h; unsigned short u; } c;
    c.h = __float2bfloat16(f);
    return c.u;
}

// ws layout (bf16 elems): WqT [128][256] @0, WkT [128][256] @32768, WvT [128][128] @65536
__global__ void transpose_weights(const float* __restrict__ Wq,
                                  const float* __restrict__ Wk,
                                  const float* __restrict__ Wv,
                                  unsigned short* __restrict__ ws) {
    int t = blockIdx.x * 256 + threadIdx.x;
    if (t < 32768) {                // Wq (256x128) -> WqT
        int k = t >> 7, c = t & 127;
        ws[c * 256 + k] = f2bf(Wq[t]);
    } else if (t < 65536) {         // Wk
        int u = t - 32768; int k = u >> 7, c = u & 127;
        ws[32768 + c * 256 + k] = f2bf(Wk[u]);
    } else if (t < 81920) {         // Wv (128x128) -> WvT
        int u = t - 65536; int k = u >> 7, c = u & 127;
        ws[65536 + c * 128 + k] = f2bf(Wv[u]);
    }
}

__global__ __launch_bounds__(1024, 4)
void attn_kernel(const float* __restrict__ query,   // (4,80,24,24,256) f32
                 const float* __restrict__ x,       // (2304,77,128) f32
                 const float* __restrict__ guid,    // (2304,77,128) f32
                 const unsigned short* __restrict__ wT,  // transposed bf16 weights
                 const float* __restrict__ bq,
                 const float* __restrict__ bk,
                 const float* __restrict__ bv,
                 float* __restrict__ out)            // (2304,128) f32
{
    const int n    = blockIdx.x;
    const int tid  = threadIdx.x;
    const int wid  = tid >> 6;      // wave 0..15
    const int lane = tid & 63;
    const int quad = lane >> 4;     // 0..3
    const int mr   = lane & 15;

    const int b  = n / 576;         // batch
    const int hw = n % 576;         // hh*24+ww

    // LDS: 42240 + 42240 + 26624 + 26624 + 512 + 2560 + 512 = 141,312 B -> 1 block/CU
    __shared__ union { unsigned short XGb[NQ * XSTR]; float Qf[NQ * QSTR]; } R0;
    __shared__ union { unsigned short Qb16[NQ * XSTR]; float KV[8][16][16]; } R1;
    __shared__ unsigned short KfT[128 * KSTR];
    __shared__ unsigned short VsT[128 * KSTR];
    __shared__ float Ksum[128];
    __shared__ float Zl[NQ * 8];
    __shared__ float Qb[128];

    const unsigned short* WqT = wT;
    const unsigned short* WkT = wT + 32768;
    const unsigned short* WvT = wT + 65536;
    const f32x4 cZ = {0.f, 0.f, 0.f, 0.f};

    const float* xg = x    + (size_t)n * S77 * 128;
    const float* gg = guid + (size_t)n * S77 * 128;

    // ================= STAGE: global f32 -> LDS bf16 (each byte read once) =========
    if (wid < 8) {
        // x rows (lanes 0-31) and guid rows (lanes 32-63), rows wid, wid+8, ...
        const float* src = (lane < 32) ? xg : gg;
        const int c4  = (lane & 31) * 4;
        const int col = (lane < 32) ? c4 : (128 + c4);
        float4 buf[10];
        #pragma unroll
        for (int k = 0; k < 10; ++k) {
            const int s = wid + 8 * k;
            if (s < S77) buf[k] = *(const float4*)(src + s * 128 + c4);
        }
        #pragma unroll
        for (int k = 0; k < 10; ++k) {
            const int s = wid + 8 * k;
            if (s < S77) {
                uint2 v; v.x = cvt_pk(buf[k].x, buf[k].y); v.y = cvt_pk(buf[k].z, buf[k].w);
                *(uint2*)&R0.XGb[s * XSTR + col] = v;
            }
        }
    } else {
        const int w8 = wid - 8;     // query rows w8, w8+8, ... (10 rows, all < 80)
        float4 buf[10];
        #pragma unroll
        for (int k = 0; k < 10; ++k) {
            const int l = w8 + 8 * k;
            buf[k] = *(const float4*)(query + ((size_t)(b * 80 + l) * 576 + hw) * 256 + lane * 4);
        }
        #pragma unroll
        for (int k = 0; k < 10; ++k) {
            const int l = w8 + 8 * k;
            uint2 v; v.x = cvt_pk(buf[k].x, buf[k].y); v.y = cvt_pk(buf[k].z, buf[k].w);
            *(uint2*)&R1.Qb16[l * XSTR + lane * 4] = v;
        }
    }
    __syncthreads();   // #1: XGb + Qb16 staged

    f32x4 accD[5];     // consumer Q-GEMM accumulators (live across barrier #2)

    if (wid < 8) {
        // ===== PRODUCERS: A1 (K GEMM, n-tile = wid), then A2 (V GEMM) =====
        bf16x8 bfk[8];
        #pragma unroll
        for (int kk = 0; kk < 8; ++kk)
            bfk[kk] = *(const bf16x8*)(WkT + (wid * 16 + mr) * 256 + kk * 32 + quad * 8);
        f32x4 acc[5];
        #pragma unroll
        for (int m = 0; m < 5; ++m) acc[m] = cZ;
        #pragma unroll
        for (int kk = 0; kk < 8; ++kk)
            #pragma unroll
            for (int m = 0; m < 5; ++m) {
                bf16x8 a = *(const bf16x8*)&R0.XGb[(m * 16 + mr) * XSTR + kk * 32 + quad * 8];
                acc[m] = __builtin_amdgcn_mfma_f32_16x16x32_bf16(a, bfk[kk], acc[m], 0, 0, 0);
            }
        const float biask = bk[wid * 16 + mr];
        float ks = 0.f;
        #pragma unroll
        for (int m = 0; m < 5; ++m) {
            float v[4];
            #pragma unroll
            for (int r = 0; r < 4; ++r) {
                const int srow = m * 16 + quad * 4 + r;
                float t = 0.f;
                if (srow < S77) {
                    t = acc[m][r] + biask;
                    t = (t > 0.f) ? (t + 1.f) : __expf(t);   // elu+1
                }
                v[r] = t; ks += t;
            }
            uint2 pv; pv.x = cvt_pk(v[0], v[1]); pv.y = cvt_pk(v[2], v[3]);
            *(uint2*)&KfT[(wid * 16 + mr) * KSTR + m * 16 + quad * 4] = pv;
        }
        ks += __shfl_down(ks, 32); ks += __shfl_down(ks, 16);
        if (lane < 16) Ksum[wid * 16 + mr] = ks;

        // A2: V = x@Wv + bv
        bf16x8 bfv[4];
        #pragma unroll
        for (int kk = 0; kk < 4; ++kk)
            bfv[kk] = *(const bf16x8*)(WvT + (wid * 16 + mr) * 128 + kk * 32 + quad * 8);
        #pragma unroll
        for (int m = 0; m < 5; ++m) acc[m] = cZ;
        #pragma unroll
        for (int kk = 0; kk < 4; ++kk)
            #pragma unroll
            for (int m = 0; m < 5; ++m) {
                bf16x8 a = *(const bf16x8*)&R0.XGb[(m * 16 + mr) * XSTR + kk * 32 + quad * 8];
                acc[m] = __builtin_amdgcn_mfma_f32_16x16x32_bf16(a, bfv[kk], acc[m], 0, 0, 0);
            }
        const float biasv = bv[wid * 16 + mr];
        #pragma unroll
        for (int m = 0; m < 5; ++m) {
            float v[4];
            #pragma unroll
            for (int r = 0; r < 4; ++r) {
                const int srow = m * 16 + quad * 4 + r;
                v[r] = (srow < S77) ? (acc[m][r] + biasv) : 0.f;
            }
            uint2 pv; pv.x = cvt_pk(v[0], v[1]); pv.y = cvt_pk(v[2], v[3]);
            *(uint2*)&VsT[(wid * 16 + mr) * KSTR + m * 16 + quad * 4] = pv;
        }
        // zero pad rows 80..95: tid<512, one uint2 (4 shorts) per array per thread
        {
            const int c = tid >> 2, part = tid & 3;
            const uint2 z = {0u, 0u};
            *(uint2*)&KfT[c * KSTR + 80 + part * 4] = z;
            *(uint2*)&VsT[c * KSTR + 80 + part * 4] = z;
        }
    } else {
        // ===== CONSUMERS: D (Q GEMM, n-tile = wid-8) from staged Qb16 =====
        const int w2 = wid - 8;
        bf16x8 bfq[8];
        #pragma unroll
        for (int kk = 0; kk < 8; ++kk)
            bfq[kk] = *(const bf16x8*)(WqT + (w2 * 16 + mr) * 256 + kk * 32 + quad * 8);
        #pragma unroll
        for (int m = 0; m < 5; ++m) accD[m] = cZ;
        #pragma unroll
        for (int kk = 0; kk < 8; ++kk)
            #pragma unroll
            for (int m = 0; m < 5; ++m) {
                bf16x8 a = *(const bf16x8*)&R1.Qb16[(m * 16 + mr) * XSTR + kk * 32 + quad * 8];
                accD[m] = __builtin_amdgcn_mfma_f32_16x16x32_bf16(a, bfq[kk], accD[m], 0, 0, 0);
            }
    }
    __syncthreads();   // #2: KfT/VsT(+pad)/Ksum ready; Qb16 dead; XGb dead

    if (wid < 8) {
        // ---- Phase C: head h = wid: KV_h = Kf_h^T @ V_h (K=96, zero-padded)
        const int h = wid;
        f32x4 acc = cZ;
        #pragma unroll
        for (int ks3 = 0; ks3 < 3; ++ks3) {
            const int sc = ks3 * 32 + quad * 8;
            bf16x8 a  = *(const bf16x8*)&KfT[(h * 16 + mr) * KSTR + sc];
            bf16x8 bb = *(const bf16x8*)&VsT[(h * 16 + mr) * KSTR + sc];
            acc = __builtin_amdgcn_mfma_f32_16x16x32_bf16(a, bb, acc, 0, 0, 0);
        }
        #pragma unroll
        for (int r = 0; r < 4; ++r) R1.KV[h][quad * 4 + r][mr] = acc[r];
    } else {
        // ---- D epilogue: Qf = elu(.+bq)+1 (f32) into R0 (XGb dead)
        const int w2 = wid - 8;
        const float biasq = bq[w2 * 16 + mr];
        #pragma unroll
        for (int m = 0; m < 5; ++m)
            #pragma unroll
            for (int r = 0; r < 4; ++r) {
                const int lrow = m * 16 + quad * 4 + r;
                float v = accD[m][r] + biasq;
                v = (v > 0.f) ? (v + 1.f) : __expf(v);
                R0.Qf[lrow * QSTR + w2 * 16 + mr] = v;
            }
    }
    __syncthreads();   // #3: KV + Qf ready

    // ---- Phase E: z_{l,h} = 1/(Qf_l,h . Ksum_h + eps)
    if (tid < NQ * 8) {
        const int l = tid >> 3, h = tid & 7;
        float d = 0.f;
        #pragma unroll
        for (int j = 0; j < 16; ++j) d += R0.Qf[l * QSTR + h * 16 + j] * Ksum[h * 16 + j];
        Zl[tid] = 1.f / (d + 1e-6f);
    }
    __syncthreads();   // #4: Zl ready

    // ---- Phase F: Qbar over all 1024 threads (8-lane partial sums + shfl reduce)
    {
        const int p = tid >> 3;     // channel 0..127 (= h*16+d)
        const int g = tid & 7;      // l-chunk 0..7 (10 rows each)
        const int h = p >> 4;
        float s = 0.f;
        #pragma unroll
        for (int l = g * 10; l < g * 10 + 10; ++l)
            s += Zl[l * 8 + h] * R0.Qf[l * QSTR + p];
        s += __shfl_xor(s, 4); s += __shfl_xor(s, 2); s += __shfl_xor(s, 1);
        if (g == 0) Qb[p] = s;
    }
    __syncthreads();   // #5: Qb ready

    if (tid < 128) {
        const int h = tid >> 4, e = tid & 15;
        float o = 0.f;
        #pragma unroll
        for (int d2 = 0; d2 < 16; ++d2) o += Qb[h * 16 + d2] * R1.KV[h][d2][e];
        out[(size_t)n * 128 + tid] = o * (1.f / 80.f);
    }
}

extern "C" void kernel_launch(void* const* d_in, const int* in_sizes, int n_in,
                              void* d_out, int out_size, void* d_ws, size_t ws_size,
                              hipStream_t stream) {
    const float* query = (const float*)d_in[0];
    const float* x     = (const float*)d_in[1];
    const float* g     = (const float*)d_in[2];
    const float* Wq    = (const float*)d_in[3];
    const float* bq    = (const float*)d_in[4];
    const float* Wk    = (const float*)d_in[5];
    const float* bk    = (const float*)d_in[6];
    const float* Wv    = (const float*)d_in[7];
    const float* bv    = (const float*)d_in[8];
    float* out = (float*)d_out;
    unsigned short* ws = (unsigned short*)d_ws;   // 163,840 B used

    hipLaunchKernelGGL(transpose_weights, dim3(320), dim3(256), 0, stream, Wq, Wk, Wv, ws);
    hipLaunchKernelGGL(attn_kernel, dim3(2304), dim3(1024), 0, stream,
                       query, x, g, ws, bq, bk, bv, out);
}